// Round 12
// baseline (25.832 us; speedup 1.0000x reference)
//
#include <hip/hip_runtime.h>

#define NS 131072
#define D 16
#define R 32
#define O 10
#define KTOT 544          // 512 affine (k=r*16+d) + 32 bias (parity-ordered)
#define EPSF 1e-8f

typedef float v2     __attribute__((ext_vector_type(2)));
typedef float f32x4  __attribute__((ext_vector_type(4)));
typedef short bf16x8 __attribute__((ext_vector_type(8)));

// f32 -> bf16 bits, round-nearest-even (prep only)
static __device__ __forceinline__ short bf(float f) {
    union { float f; unsigned u; } v; v.f = f;
    unsigned r = (v.u + 0x7fffu + ((v.u >> 16) & 1u)) >> 16;
    return (short)r;
}

// packed f32x2 -> bf16x2 in one HW instr
static __device__ __forceinline__ unsigned cvtpk(float lo, float hi) {
    unsigned r;
    asm("v_cvt_pk_bf16_f32 %0, %1, %2" : "=v"(r) : "v"(lo), "v"(hi));
    return r;
}

// prep: nw=-1/(2s^2), nm1=c/s^2, nc0[r]=sum_d w c^2, Ct[o][k] bf16 (16 x 544).
// k<512: r=k>>4, d=k&15. k>=512 bias, PARITY-ORDERED slots: t=k-512,
// rule = (t<16) ? 2t : 2(t-16)+1  — so lane (g,c) owns its bias rules.
__global__ void anfis_prep(const float* __restrict__ sigmas,
                           const float* __restrict__ centers,
                           const float* __restrict__ coeffs,
                           float* __restrict__ nw,
                           float* __restrict__ nm1,
                           float* __restrict__ nc0,
                           unsigned short* __restrict__ Ct) {
    int i = blockIdx.x * blockDim.x + threadIdx.x;
    if (i < R * D) {
        float s = sigmas[i], c = centers[i];
        float w = -0.5f / (s * s);
        nw[i]  = w;
        nm1[i] = -2.0f * w * c;
    }
    if (i < R) {
        float acc = 0.f;
        for (int d = 0; d < D; ++d) {
            float s = sigmas[i * D + d], c = centers[i * D + d];
            acc += (-0.5f / (s * s)) * c * c;
        }
        nc0[i] = acc;
    }
    if (i < 16 * KTOT) {
        int o = i / KTOT, k = i % KTOT;
        float v = 0.f;
        if (o < O) {
            if (k < R * D) {
                int r = k >> 4, d = k & 15;
                v = coeffs[(r * (D + 1) + d) * O + o];
            } else {
                int t = k - 512;
                int r = (t < 16) ? (2 * t) : (2 * (t - 16) + 1);
                v = coeffs[(r * (D + 1) + D) * O + o];
            }
        }
        Ct[i] = (unsigned short)bf(v);
    }
}

// Phase 1 (cooperative): lane = sample blk0+lane, wave w computes rules
// [8w,8w+8) (wave-uniform SMEM params) -> s into stile[32][64], psum -> sbuf.
// ONE barrier.
// Phase 2 (per-wave independent): wave w owns samples 16w..16w+15.
// Lane 16g+c builds its A-fragment (row c, k-slots 8g..8g+8) IN REGISTERS:
// rules of parity g>>1, d-half g&1 -> no Z staging, no rt loop, 17 MFMA of
// one tile, acc = 4 VGPRs. Softmax via 16-lane shfl reduce; all waves store.
__global__ __launch_bounds__(256, 6) void anfis_main(
    const float* __restrict__ X,
    const float* __restrict__ nw,
    const float* __restrict__ nm1,
    const float* __restrict__ nc0,
    const unsigned short* __restrict__ Ct,
    float* __restrict__ out)
{
    const int tid  = threadIdx.x;
    const int lane = tid & 63;
    const int w    = __builtin_amdgcn_readfirstlane(tid >> 6);
    const int blk0 = blockIdx.x * 64;

    __shared__ float stile[R * 64];   // s[rule][sample] : 8 KB
    __shared__ float sbuf[256];       // per-wave psum partials

    // ======== phase 1: membership (lane = sample blk0+lane) ========
    {
        v2 x2[8];
        const float4* xp = reinterpret_cast<const float4*>(X + (size_t)(blk0 + lane) * D);
        #pragma unroll
        for (int i = 0; i < 4; ++i) {
            float4 v = xp[i];
            x2[2*i]   = v2{v.x, v.y};
            x2[2*i+1] = v2{v.z, v.w};
        }
        const int r0 = w * 8;
        float psum = 0.f;
        #pragma unroll
        for (int j = 0; j < 8; ++j) {
            const int r = r0 + j;
            const v2* W2 = reinterpret_cast<const v2*>(nw  + r * D);
            const v2* M2 = reinterpret_cast<const v2*>(nm1 + r * D);
            v2 e2 = v2{0.f, 0.f};
            #pragma unroll
            for (int i = 0; i < 8; ++i) {
                // e += x*(w*x + m1)  (Horner: no x^2 array)
                v2 t = __builtin_elementwise_fma(W2[i], x2[i], M2[i]);
                e2 = __builtin_elementwise_fma(t, x2[i], e2);
            }
            float s = __expf(e2.x + e2.y + nc0[r]);
            psum += s;
            stile[r * 64 + lane] = s;   // bank = lane%32: conflict-free
        }
        sbuf[tid] = psum;
    }
    __syncthreads();

    // ======== phase 2: per-wave, fully independent ========
    const int c   = lane & 15;
    const int g   = lane >> 4;
    const int par = g >> 1;          // rule parity this lane needs
    const int dh  = (g & 1) * 8;     // d-half base
    const int sm  = w * 16 + c;      // block-sample whose A-row this lane builds

    // x half of sample sm (L1-hot reload)
    float xh[8];
    {
        const float* xp2 = X + (size_t)(blk0 + sm) * D + dh;
        float4 xa = *reinterpret_cast<const float4*>(xp2);
        float4 xb = *reinterpret_cast<const float4*>(xp2 + 4);
        xh[0]=xa.x; xh[1]=xa.y; xh[2]=xa.z; xh[3]=xa.w;
        xh[4]=xb.x; xh[5]=xb.y; xh[6]=xb.z; xh[7]=xb.w;
    }

    // 16 strengths of this lane's parity set: sv[t] = s[2t+par][sm]
    float sv[16];
    #pragma unroll
    for (int t = 0; t < 16; ++t)
        sv[t] = stile[(2 * t + par) * 64 + sm];   // 2-way bank alias: free

    // inv for this lane's OUTPUT samples 16w+4g+j
    float inv[4];
    #pragma unroll
    for (int j = 0; j < 4; ++j) {
        const int so = w * 16 + 4 * g + j;
        float tot = sbuf[so] + sbuf[64 + so] + sbuf[128 + so] + sbuf[192 + so];
        inv[j] = __builtin_amdgcn_rcpf(tot + EPSF);
    }

    // ---- consequent: 17 K-steps, A built in-register ----
    const unsigned short* cbase = Ct + c * KTOT + g * 8;
    f32x4 acc = f32x4{0.f, 0.f, 0.f, 0.f};
    bf16x8 bnext = *reinterpret_cast<const bf16x8*>(cbase);
    #pragma unroll
    for (int p = 0; p <= 16; ++p) {
        bf16x8 bcur = bnext;
        if (p < 16) bnext = *reinterpret_cast<const bf16x8*>(cbase + 32 * (p + 1));
        union { unsigned u[4]; bf16x8 v; } A;
        if (p < 16) {
            // affine: k = 32p+8g+j  ->  rule 2p+par (= sv[p]), d = dh+j
            const float sp = sv[p];
            #pragma unroll
            for (int m = 0; m < 4; ++m)
                A.u[m] = cvtpk(sp * xh[2*m], sp * xh[2*m+1]);
        } else {
            // bias: parity-ordered slots; lane's 8 slots = sv[8*(g&1) .. +8]
            const int b0 = 8 * (g & 1);
            #pragma unroll
            for (int m = 0; m < 4; ++m)
                A.u[m] = cvtpk(sv[b0 + 2*m], sv[b0 + 2*m+1]);
        }
        acc = __builtin_amdgcn_mfma_f32_16x16x32_bf16(A.v, bcur, acc, 0, 0, 0);
    }

    // ---- epilogue (all waves): lane holds logits of samples 16w+4g+j, o=c ----
    float a[4], ev[4], red[4];
    #pragma unroll
    for (int j = 0; j < 4; ++j) {
        a[j]   = acc[j] * inv[j];
        red[j] = (c < O) ? a[j] : -1e30f;
    }
    #pragma unroll
    for (int bit = 1; bit <= 8; bit <<= 1) {
        #pragma unroll
        for (int j = 0; j < 4; ++j) red[j] = fmaxf(red[j], __shfl_xor(red[j], bit));
    }
    #pragma unroll
    for (int j = 0; j < 4; ++j) ev[j] = (c < O) ? __expf(a[j] - red[j]) : 0.f;
    #pragma unroll
    for (int j = 0; j < 4; ++j) red[j] = ev[j];
    #pragma unroll
    for (int bit = 1; bit <= 8; bit <<= 1) {
        #pragma unroll
        for (int j = 0; j < 4; ++j) red[j] += __shfl_xor(red[j], bit);
    }
    if (c < O) {
        #pragma unroll
        for (int j = 0; j < 4; ++j) {
            const float rs = __builtin_amdgcn_rcpf(red[j]);
            out[(size_t)(blk0 + w * 16 + 4 * g + j) * O + c] = ev[j] * rs;
        }
    }
}

extern "C" void kernel_launch(void* const* d_in, const int* in_sizes, int n_in,
                              void* d_out, int out_size, void* d_ws, size_t ws_size,
                              hipStream_t stream) {
    const float* X       = (const float*)d_in[0];
    const float* centers = (const float*)d_in[1];
    const float* sigmas  = (const float*)d_in[2];
    const float* coeffs  = (const float*)d_in[3];
    float* out = (float*)d_out;

    float* nw  = (float*)d_ws;                                   // 512 f32 @ 0
    float* nm1 = (float*)((char*)d_ws + 2048);                   // 512 f32
    float* nc0 = (float*)((char*)d_ws + 4096);                   // 32 f32
    unsigned short* Ct = (unsigned short*)((char*)d_ws + 4224);  // 16*544 bf16

    anfis_prep<<<(16 * KTOT + 255) / 256, 256, 0, stream>>>(sigmas, centers, coeffs,
                                                            nw, nm1, nc0, Ct);
    anfis_main<<<NS / 64, 256, 0, stream>>>(X, nw, nm1, nc0, Ct, out);
}

// Round 13
// 24.073 us; speedup vs baseline: 1.0731x; 1.0731x over previous
//
#include <hip/hip_runtime.h>

#define NS 131072
#define D 16
#define R 32
#define O 10
#define KTOT 544          // R*D (affine) + R (bias block)
#define EPSF 1e-8f

typedef float v2     __attribute__((ext_vector_type(2)));
typedef float f32x4  __attribute__((ext_vector_type(4)));
typedef short bf16x8 __attribute__((ext_vector_type(8)));

// f32 -> bf16 bits, round-nearest-even (prep only)
static __device__ __forceinline__ short bf(float f) {
    union { float f; unsigned u; } v; v.f = f;
    unsigned r = (v.u + 0x7fffu + ((v.u >> 16) & 1u)) >> 16;
    return (short)r;
}

// packed f32x2 -> bf16x2 in one HW instr
static __device__ __forceinline__ unsigned cvtpk(float lo, float hi) {
    unsigned r;
    asm("v_cvt_pk_bf16_f32 %0, %1, %2" : "=v"(r) : "v"(lo), "v"(hi));
    return r;
}

// prep: nw=-1/(2s^2), nm1=c/s^2, nc0[r]=sum_d w c^2, Ct[o][k] bf16 (16 x 544)
__global__ void anfis_prep(const float* __restrict__ sigmas,
                           const float* __restrict__ centers,
                           const float* __restrict__ coeffs,
                           float* __restrict__ nw,
                           float* __restrict__ nm1,
                           float* __restrict__ nc0,
                           unsigned short* __restrict__ Ct) {
    int i = blockIdx.x * blockDim.x + threadIdx.x;
    if (i < R * D) {
        float s = sigmas[i], c = centers[i];
        float w = -0.5f / (s * s);
        nw[i]  = w;
        nm1[i] = -2.0f * w * c;
    }
    if (i < R) {
        float acc = 0.f;
        for (int d = 0; d < D; ++d) {
            float s = sigmas[i * D + d], c = centers[i * D + d];
            acc += (-0.5f / (s * s)) * c * c;
        }
        nc0[i] = acc;
    }
    if (i < 16 * KTOT) {
        int o = i / KTOT, k = i % KTOT;
        float v = 0.f;
        if (o < O) {
            if (k < R * D) { int r = k >> 4, d = k & 15; v = coeffs[(r * (D + 1) + d) * O + o]; }
            else           { int r = k - R * D;          v = coeffs[(r * (D + 1) + D) * O + o]; }
        }
        Ct[i] = (unsigned short)bf(v);
    }
}

// R11 structure VERBATIM, single change: launch_bounds (256,4) -> (256,6).
// 4 waves x 64 samples; wave w owns rules [8w,8w+8); membership on VALU;
// consequent via 5 MFMA phases on UNNORMALIZED Z = s*x in wave-private
// swizzled LDS; 1/(sum s + eps) folded into the epilogue logits; 1 barrier.
__global__ __launch_bounds__(256, 6) void anfis_main(
    const float* __restrict__ X,
    const float* __restrict__ nw,
    const float* __restrict__ nm1,
    const float* __restrict__ nc0,
    const unsigned short* __restrict__ Ct,
    float* __restrict__ out)
{
    const int tid  = threadIdx.x;
    const int lane = tid & 63;
    const int w    = __builtin_amdgcn_readfirstlane(tid >> 6);
    const int n    = blockIdx.x * 64 + lane;

    // per-wave 4352B region: Z (64 x 4 x 16B = 4096B), then C-partials
    // overlaid column-major red[o*69 + row] (10 x 69 x 4B = 2760B).
    __shared__ char  lbuf[4 * 4352];
    __shared__ float sbuf[256];
    bf16x8* zw = reinterpret_cast<bf16x8*>(lbuf + w * 4352);
    float*  rw = reinterpret_cast<float*> (lbuf + w * 4352);

    // ---- load x ----
    v2 x2[8];
    {
        const float4* xp = reinterpret_cast<const float4*>(X + (size_t)n * D);
        #pragma unroll
        for (int i = 0; i < 4; ++i) {
            float4 v = xp[i];
            x2[2*i]   = v2{v.x, v.y};
            x2[2*i+1] = v2{v.z, v.w};
        }
    }

    // ---- B prefetch for phase 0 ----
    const int o = lane & 15, g = lane >> 4;
    const unsigned short* cbase = Ct + o * KTOT + g * 8;
    bf16x8 bnext = *reinterpret_cast<const bf16x8*>(cbase + w * 128);

    // ---- membership: e = sum_d (w x^2 + m1 x) + c0 ; s UNNORMALIZED ----
    float s[8];
    {
        const int r0 = w * 8;
        float psum = 0.f;
        #pragma unroll
        for (int j = 0; j < 8; ++j) {
            const int r = r0 + j;
            const v2* W2 = reinterpret_cast<const v2*>(nw  + r * D);
            const v2* M2 = reinterpret_cast<const v2*>(nm1 + r * D);
            v2 e2 = v2{0.f, 0.f};
            #pragma unroll
            for (int i = 0; i < 8; ++i) {
                e2 = __builtin_elementwise_fma(x2[i] * x2[i], W2[i], e2);
                e2 = __builtin_elementwise_fma(x2[i],         M2[i], e2);
            }
            s[j] = __expf(e2.x + e2.y + nc0[r]);
            psum += s[j];
        }
        sbuf[tid] = psum;   // consumed only after the single barrier (epilogue)
    }

    f32x4 acc[4];
    #pragma unroll
    for (int rt = 0; rt < 4; ++rt) acc[rt] = f32x4{0.f, 0.f, 0.f, 0.f};

    #define ZPHYS(row, chunk) ((((row) * 4 + (chunk)) ^ (((row) >> 1) & 7)))

    // ---- 5 phases: p<4 => 2 rules (K=32); p==4 => bias block ----
    #pragma unroll
    for (int p = 0; p < 5; ++p) {
        bf16x8 bcur = bnext;
        if (p < 4) {
            const int k0n = (p + 1 < 4) ? (w * 128 + (p + 1) * 32) : (R * D);
            bnext = *reinterpret_cast<const bf16x8*>(cbase + k0n);
        }
        if (p < 4) {
            // z[k=q*16+d] = s[2p+q]*x[d]; chunk j: rule q=j>>1, d-range (j&1)*8..+8
            #pragma unroll
            for (int j = 0; j < 4; ++j) {
                const float nq = s[2 * p + (j >> 1)];
                union { unsigned u[4]; bf16x8 v; } ch;
                #pragma unroll
                for (int m = 0; m < 4; ++m) {
                    v2 t = x2[(j & 1) * 4 + m] * nq;
                    ch.u[m] = cvtpk(t.x, t.y);
                }
                zw[ZPHYS(lane, j)] = ch.v;
            }
        } else {
            // bias: k-slot g*8+e <-> rule g*8+e; this wave supplies chunk w only
            #pragma unroll
            for (int j = 0; j < 4; ++j) {
                union { unsigned u[4]; bf16x8 v; } ch;
                #pragma unroll
                for (int m = 0; m < 4; ++m)
                    ch.u[m] = (j == w) ? cvtpk(s[2 * m], s[2 * m + 1]) : 0u;
                zw[ZPHYS(lane, j)] = ch.v;
            }
        }
        #pragma unroll
        for (int rt = 0; rt < 4; ++rt) {
            bf16x8 af = zw[ZPHYS((lane & 15) + rt * 16, g)];
            acc[rt] = __builtin_amdgcn_mfma_f32_16x16x32_bf16(af, bcur, acc[rt], 0, 0, 0);
        }
    }

    // ---- stash C-partials, transposed: red[o*69 + row], rows contiguous ----
    if (o < O) {
        #pragma unroll
        for (int rt = 0; rt < 4; ++rt) {
            *reinterpret_cast<f32x4*>(rw + o * 69 + rt * 16 + g * 4) = acc[rt];
        }
    }
    __syncthreads();   // the ONLY barrier

    // ---- epilogue: wave 0, lane = sample; late normalization + softmax ----
    if (tid < 64) {
        const float tot = sbuf[tid] + sbuf[tid + 64] + sbuf[tid + 128] + sbuf[tid + 192];
        const float inv = __builtin_amdgcn_rcpf(tot + EPSF);
        float a[O];
        #pragma unroll
        for (int oo = 0; oo < O; ++oo) {
            a[oo] = (reinterpret_cast<const float*>(lbuf +    0)[oo * 69 + tid]
                   + reinterpret_cast<const float*>(lbuf + 4352)[oo * 69 + tid]
                   + reinterpret_cast<const float*>(lbuf + 8704)[oo * 69 + tid]
                   + reinterpret_cast<const float*>(lbuf +13056)[oo * 69 + tid]) * inv;
        }
        float m = a[0];
        #pragma unroll
        for (int oo = 1; oo < O; ++oo) m = fmaxf(m, a[oo]);
        float e_[O]; float se = 0.f;
        #pragma unroll
        for (int oo = 0; oo < O; ++oo) { e_[oo] = __expf(a[oo] - m); se += e_[oo]; }
        const float rs = __builtin_amdgcn_rcpf(se);
        float2* op = reinterpret_cast<float2*>(out + (size_t)(blockIdx.x * 64 + tid) * O);
        #pragma unroll
        for (int pp = 0; pp < 5; ++pp) op[pp] = make_float2(e_[2*pp] * rs, e_[2*pp+1] * rs);
    }
}

extern "C" void kernel_launch(void* const* d_in, const int* in_sizes, int n_in,
                              void* d_out, int out_size, void* d_ws, size_t ws_size,
                              hipStream_t stream) {
    const float* X       = (const float*)d_in[0];
    const float* centers = (const float*)d_in[1];
    const float* sigmas  = (const float*)d_in[2];
    const float* coeffs  = (const float*)d_in[3];
    float* out = (float*)d_out;

    float* nw  = (float*)d_ws;                                   // 512 f32 @ 0
    float* nm1 = (float*)((char*)d_ws + 2048);                   // 512 f32
    float* nc0 = (float*)((char*)d_ws + 4096);                   // 32 f32
    unsigned short* Ct = (unsigned short*)((char*)d_ws + 4224);  // 16*544 bf16

    anfis_prep<<<(16 * KTOT + 255) / 256, 256, 0, stream>>>(sigmas, centers, coeffs,
                                                            nw, nm1, nc0, Ct);
    anfis_main<<<NS / 64, 256, 0, stream>>>(X, nw, nm1, nc0, Ct, out);
}